// Round 6
// baseline (2584.849 us; speedup 1.0000x reference)
//
#include <hip/hip_runtime.h>
#include <hip/hip_bf16.h>

#define TSEQ  512
#define BATCH 64
#define HIDN  512
#define EMBD  100
#define NWG   64

typedef __attribute__((ext_vector_type(8))) short short8;
typedef __attribute__((ext_vector_type(4))) float f32x4;
typedef unsigned int u32;
typedef __attribute__((ext_vector_type(4))) u32 u32x4;

// ---- workspace layout (bytes) ----
#define A_OFF   0ull                 // 512*64*512 bf16 = 33,554,432
#define HD_OFF  33554432ull          // 512*64*512 bf16 = 33,554,432
#define HB_OFF  67108864ull          // tagged granules: 2*64wg*64row*2*16B = 262,144
#define FLG_OFF 67371008ull          // 64 flags * 64B pad = 4,096
#define KEY_OFF 67375104ull          // 6400 * 4 = 25,600
#define DW_OFF  67400704ull          // 112*512*2 = 114,688
#define ZERO_SPAN 291840ull          // HB + FLG + KEY

static __device__ __forceinline__ unsigned short f2bfbits(float f) {
    u32 u = __float_as_uint(f);
    u32 r = (u + 0x7fffu + ((u >> 16) & 1u)) >> 16;   // round-to-nearest-even
    return (unsigned short)r;
}

static __device__ __forceinline__ float sigf(float x) {
    return __builtin_amdgcn_rcpf(1.0f + __expf(-x));
}
static __device__ __forceinline__ float tanhfast(float x) {
    float t = __expf(-2.0f * fabsf(x));               // in (0,1], no overflow
    float r = (1.0f - t) * __builtin_amdgcn_rcpf(1.0f + t);
    return copysignf(r, x);
}

// ---------------- K1: dec_w -> bf16 (padded to 112 rows with zeros) ----------
__global__ void k_dw(const float* __restrict__ dw, unsigned short* __restrict__ dwb) {
    int i = blockIdx.x * 256 + threadIdx.x;            // 57,344 = 112*512
    float v = (i < EMBD * HIDN) ? dw[i] : 0.0f;
    dwb[i] = f2bfbits(v);
}

// ---------------- K2: embedding gather -> bf16 A[t][b][k] --------------------
__global__ void k_embed(const int* __restrict__ x, const float* __restrict__ emb,
                        unsigned short* __restrict__ A) {
    int g = blockIdx.x * 256 + threadIdx.x;            // 2,097,152 = T*B*64
    int k8 = g & 63;
    int bt = g >> 6;                                   // t*64 + b
    int b  = bt & 63;
    int t  = bt >> 6;
    int row = x[b * TSEQ + t];
    const float4* src = reinterpret_cast<const float4*>(emb + (size_t)row * HIDN + k8 * 8);
    float4 v0 = src[0], v1 = src[1];
    short8 s;
    s[0] = (short)f2bfbits(v0.x); s[1] = (short)f2bfbits(v0.y);
    s[2] = (short)f2bfbits(v0.z); s[3] = (short)f2bfbits(v0.w);
    s[4] = (short)f2bfbits(v1.x); s[5] = (short)f2bfbits(v1.y);
    s[6] = (short)f2bfbits(v1.z); s[7] = (short)f2bfbits(v1.w);
    *reinterpret_cast<short8*>(A + (size_t)g * 8) = s;
}

// ---------------- K3: persistent LSTM+BN+dropout ----------------------------
// 64 WGs x 512 threads. WG wg owns h-columns [wg*8, wg*8+8).
// Wave w: mh = w&1 (32-row M half), kq = w>>1 (128-col K quarter of BOTH
// the A and H halves). ~210 VGPR, only vmcnt(0) waits (spill-robust).
// h exchange, HYBRID protocol:
//   writer: tagged granules {data,tag,data,tag} sc1 -> BN -> vmcnt(0) ack ->
//           flag store (round-3-proven ordering).
//   reader: speculative granule loads + tag check, <=6 BOUNDED retries;
//           fallback = flag poll + full reload (guaranteed liveness).
// No unbounded data-dependent loop exists on the tag path.
__launch_bounds__(512, 1)
__global__ void k_lstm(const float* __restrict__ wih, const float* __restrict__ whh,
                       const float* __restrict__ bih, const float* __restrict__ bhh,
                       const float* __restrict__ gamma, const float* __restrict__ beta,
                       const float* __restrict__ mask,
                       const unsigned short* __restrict__ A,
                       u32* __restrict__ hx,
                       unsigned short* __restrict__ hd,
                       u32* __restrict__ flg) {
    const int tid  = threadIdx.x;
    const int wg   = blockIdx.x;
    const int lane = tid & 63;
    const int w    = tid >> 6;        // wave 0..7
    const int mh   = w & 1;
    const int kq   = w >> 1;

    __shared__ float gbuf[4][64][33];                       // partial gates (kq slices)
    __shared__ __align__(16) unsigned short hstage[64][8];
    __shared__ __align__(16) unsigned short hdstage[2][64][8];

    const int l15 = lane & 15;
    const int lk8 = (lane >> 4) * 8;

    // ---- load static B fragments into registers (once): K quarter kq ----
    short8 bfrA[4][2], bfrH[4][2];
    #pragma unroll
    for (int kk = 0; kk < 4; ++kk) {
        #pragma unroll
        for (int nb = 0; nb < 2; ++nb) {
            int nl   = nb * 16 + l15;                 // local gate col 0..31
            int gate = nl >> 3, jl = nl & 7;
            int ng   = gate * HIDN + wg * 8 + jl;     // row of w_ih/w_hh [4H, H]
            int kl   = kq * 128 + kk * 32 + lk8;      // K column 0..511
            const float* pa = wih + (size_t)ng * HIDN + kl;
            const float* ph = whh + (size_t)ng * HIDN + kl;
            short8 ba, bh;
            #pragma unroll
            for (int e = 0; e < 8; ++e) { ba[e] = (short)f2bfbits(pa[e]); bh[e] = (short)f2bfbits(ph[e]); }
            bfrA[kk][nb] = ba;
            bfrH[kk][nb] = bh;
        }
    }

    // ---- pointwise-role constants ----
    const int jj = wg * 8 + w;
    const float bias_i = bih[jj]          + bhh[jj];
    const float bias_f = bih[512 + jj]    + bhh[512 + jj];
    const float bias_g = bih[1024 + jj]   + bhh[1024 + jj];
    const float bias_o = bih[1536 + jj]   + bhh[1536 + jj];
    const float gam = gamma[jj], bet = beta[jj];
    const float mk  = mask[(size_t)lane * HIDN + jj] * (1.0f / 0.7f);
    float c = 0.0f;

    const int arow0 = mh * 32 + l15;  // M row of fragment f=0 (f=1: +16)
    const u32* fpoll = flg + lane * 16;

    // ---- prologue: gbuf[kq] = A(0) @ Wih^T (kq slice, both M fragments) ----
    #pragma unroll
    for (int f = 0; f < 2; ++f) {
        const unsigned short* abase = A + (size_t)(arow0 + f * 16) * HIDN + kq * 128;
        f32x4 a0 = {0.f,0.f,0.f,0.f}, a1 = {0.f,0.f,0.f,0.f};
        #pragma unroll
        for (int kk = 0; kk < 4; ++kk) {
            short8 a = *reinterpret_cast<const short8*>(abase + kk * 32 + lk8);
            a0 = __builtin_amdgcn_mfma_f32_16x16x32_bf16(a, bfrA[kk][0], a0, 0, 0, 0);
            a1 = __builtin_amdgcn_mfma_f32_16x16x32_bf16(a, bfrA[kk][1], a1, 0, 0, 0);
        }
        #pragma unroll
        for (int r = 0; r < 4; ++r) {
            int row = mh * 32 + f * 16 + (lane >> 4) * 4 + r;
            gbuf[kq][row][l15]      = a0[r];
            gbuf[kq][row][16 + l15] = a1[r];
        }
    }
    __syncthreads();

    for (int s = 0; s < TSEQ; ++s) {
        // ---- pointwise: gates(s) -> c, h(s+1) (critical path) ----
        float gi = gbuf[0][lane][w]      + gbuf[1][lane][w]
                 + gbuf[2][lane][w]      + gbuf[3][lane][w]      + bias_i;
        float gf = gbuf[0][lane][8 + w]  + gbuf[1][lane][8 + w]
                 + gbuf[2][lane][8 + w]  + gbuf[3][lane][8 + w]  + bias_f;
        float gg = gbuf[0][lane][16 + w] + gbuf[1][lane][16 + w]
                 + gbuf[2][lane][16 + w] + gbuf[3][lane][16 + w] + bias_g;
        float go = gbuf[0][lane][24 + w] + gbuf[1][lane][24 + w]
                 + gbuf[2][lane][24 + w] + gbuf[3][lane][24 + w] + bias_o;
        float iv = sigf(gi), fv = sigf(gf), gv = tanhfast(gg), ov = sigf(go);
        c = fv * c + iv * gv;
        float h = ov * tanhfast(c);
        hstage[lane][w] = f2bfbits(h);
        __syncthreads();                                        // [A]

        const int last = (s == TSEQ - 1);
        const int sb   = (s + 1) & 1;
        const u32 tgt  = (u32)(s + 1);

        short8 af[4][2];
        u32x4  g0[4][2], g1[4][2];

        if (!last) {
            // ---- wave0: publish h(s+1) as tagged granules ----
            if (w == 0) {
                const u32* hrow = reinterpret_cast<const u32*>(&hstage[lane][0]);
                u32 a0 = hrow[0], a1 = hrow[1], a2 = hrow[2], a3 = hrow[3];
                u32x4 q0 = {a0, tgt, a1, tgt};                  // {cols0-1,tag,cols2-3,tag}
                u32x4 q1 = {a2, tgt, a3, tgt};                  // {cols4-5,tag,cols6-7,tag}
                u32* dst = hx + (((size_t)sb * NWG + wg) * 64 + lane) * 8;
                asm volatile("global_store_dwordx4 %0, %1, off sc1" :: "v"(dst), "v"(q0) : "memory");
                asm volatile("global_store_dwordx4 %0, %1, off sc1" :: "v"(dst + 4), "v"(q1) : "memory");
            }
            // ---- speculative loads: A(s+1) (8) and granules (16) ----
            #pragma unroll
            for (int f = 0; f < 2; ++f) {
                const unsigned short* abase =
                    A + ((size_t)(s + 1) * 64 + arow0 + f * 16) * HIDN + kq * 128;
                #pragma unroll
                for (int kk = 0; kk < 4; ++kk) {
                    const unsigned short* p = abase + kk * 32 + lk8;
                    asm volatile("global_load_dwordx4 %0, %1, off" : "=v"(af[kk][f]) : "v"(p) : "memory");
                }
            }
            #pragma unroll
            for (int f = 0; f < 2; ++f) {
                #pragma unroll
                for (int kk = 0; kk < 4; ++kk) {
                    int wgp = kq * 16 + kk * 4 + (lane >> 4);
                    const u32* p = hx + (((size_t)sb * NWG + wgp) * 64 + arow0 + f * 16) * 8;
                    asm volatile("global_load_dwordx4 %0, %1, off sc1" : "=v"(g0[kk][f]) : "v"(p) : "memory");
                    asm volatile("global_load_dwordx4 %0, %1, off sc1" : "=v"(g1[kk][f]) : "v"(p + 4) : "memory");
                }
            }
        }

        // ---- BatchNorm + locked dropout (fills the store/load flight) ----
        {
            float s1 = h, s2 = h * h;
            #pragma unroll
            for (int m = 1; m < 64; m <<= 1) {
                s1 += __shfl_xor(s1, m, 64);
                s2 += __shfl_xor(s2, m, 64);
            }
            float mu  = s1 * (1.0f / 64.0f);
            float var = s2 * (1.0f / 64.0f) - mu * mu;
            float hn  = (h - mu) * rsqrtf(var + 1e-5f) * gam + bet;
            hdstage[s & 1][lane][w] = f2bfbits(hn * mk);
        }

        if (!last) {
            asm volatile("s_waitcnt vmcnt(0)" ::: "memory");    // acks stores too
            __builtin_amdgcn_sched_barrier(0);
            // ---- wave0 lane0: publish flag (after h-store ack: round-3 order)
            if (w == 0 && lane == 0) {
                const u32* myf = flg + wg * 16;
                asm volatile("global_store_dword %0, %1, off sc1" :: "v"(myf), "v"(tgt) : "memory");
            }

            // ---- tag check: fast path + <=6 bounded retries ----
            int ok;
            {
                int o = 1;
                #pragma unroll
                for (int f = 0; f < 2; ++f)
                    #pragma unroll
                    for (int kk = 0; kk < 4; ++kk)
                        o &= (g0[kk][f].y == tgt) & (g0[kk][f].w == tgt)
                           & (g1[kk][f].y == tgt) & (g1[kk][f].w == tgt);
                ok = __all(o);
            }
            #pragma unroll 1
            for (int att = 0; att < 6 && !ok; ++att) {
                #pragma unroll
                for (int f = 0; f < 2; ++f) {
                    #pragma unroll
                    for (int kk = 0; kk < 4; ++kk) {
                        int wgp = kq * 16 + kk * 4 + (lane >> 4);
                        const u32* p = hx + (((size_t)sb * NWG + wgp) * 64 + arow0 + f * 16) * 8;
                        if ((g0[kk][f].y != tgt) | (g0[kk][f].w != tgt))
                            asm volatile("global_load_dwordx4 %0, %1, off sc1" : "=v"(g0[kk][f]) : "v"(p) : "memory");
                        if ((g1[kk][f].y != tgt) | (g1[kk][f].w != tgt))
                            asm volatile("global_load_dwordx4 %0, %1, off sc1" : "=v"(g1[kk][f]) : "v"(p + 4) : "memory");
                    }
                }
                asm volatile("s_waitcnt vmcnt(0)" ::: "memory");
                __builtin_amdgcn_sched_barrier(0);
                int o = 1;
                #pragma unroll
                for (int f = 0; f < 2; ++f)
                    #pragma unroll
                    for (int kk = 0; kk < 4; ++kk)
                        o &= (g0[kk][f].y == tgt) & (g0[kk][f].w == tgt)
                           & (g1[kk][f].y == tgt) & (g1[kk][f].w == tgt);
                ok = __all(o);
            }
            if (!ok) {
                // ---- fallback: proven flag protocol (guaranteed liveness) ----
                u32 v;
                do {
                    asm volatile("global_load_dword %0, %1, off sc1" : "=v"(v) : "v"(fpoll) : "memory");
                    asm volatile("s_waitcnt vmcnt(0)" ::: "memory");
                } while (!__all((int)(v >= tgt)));
                __builtin_amdgcn_sched_barrier(0);
                #pragma unroll
                for (int f = 0; f < 2; ++f) {
                    #pragma unroll
                    for (int kk = 0; kk < 4; ++kk) {
                        int wgp = kq * 16 + kk * 4 + (lane >> 4);
                        const u32* p = hx + (((size_t)sb * NWG + wgp) * 64 + arow0 + f * 16) * 8;
                        asm volatile("global_load_dwordx4 %0, %1, off sc1" : "=v"(g0[kk][f]) : "v"(p) : "memory");
                        asm volatile("global_load_dwordx4 %0, %1, off sc1" : "=v"(g1[kk][f]) : "v"(p + 4) : "memory");
                    }
                }
                asm volatile("s_waitcnt vmcnt(0)" ::: "memory");
                __builtin_amdgcn_sched_barrier(0);
            }

            // ---- MFMAs: A slice then H slice, accumulate -> gbuf[kq] ----
            f32x4 acc[2][2];
            #pragma unroll
            for (int f = 0; f < 2; ++f)
                #pragma unroll
                for (int nb = 0; nb < 2; ++nb) acc[f][nb] = (f32x4){0.f,0.f,0.f,0.f};
            #pragma unroll
            for (int f = 0; f < 2; ++f) {
                #pragma unroll
                for (int kk = 0; kk < 4; ++kk) {
                    acc[f][0] = __builtin_amdgcn_mfma_f32_16x16x32_bf16(af[kk][f], bfrA[kk][0], acc[f][0], 0, 0, 0);
                    acc[f][1] = __builtin_amdgcn_mfma_f32_16x16x32_bf16(af[kk][f], bfrA[kk][1], acc[f][1], 0, 0, 0);
                }
            }
            #pragma unroll
            for (int f = 0; f < 2; ++f) {
                #pragma unroll
                for (int kk = 0; kk < 4; ++kk) {
                    u32x4 q = {g0[kk][f].x, g0[kk][f].z, g1[kk][f].x, g1[kk][f].z};
                    short8 a = *reinterpret_cast<short8*>(&q);
                    acc[f][0] = __builtin_amdgcn_mfma_f32_16x16x32_bf16(a, bfrH[kk][0], acc[f][0], 0, 0, 0);
                    acc[f][1] = __builtin_amdgcn_mfma_f32_16x16x32_bf16(a, bfrH[kk][1], acc[f][1], 0, 0, 0);
                }
            }
            #pragma unroll
            for (int f = 0; f < 2; ++f) {
                #pragma unroll
                for (int r = 0; r < 4; ++r) {
                    int row = mh * 32 + f * 16 + (lane >> 4) * 4 + r;
                    gbuf[kq][row][l15]      = acc[f][0][r];
                    gbuf[kq][row][16 + l15] = acc[f][1][r];
                }
            }
        }
        __syncthreads();                                        // [B]

        // ---- wave1 drains hd(s) (reads cross-wave hdstage, post-[B]) ----
        if (w == 1) {
            short8 dv = *reinterpret_cast<const short8*>(&hdstage[s & 1][lane][0]);
            *reinterpret_cast<short8*>(hd + ((size_t)s * 64 + lane) * HIDN + wg * 8) = dv;
        }
    }
}

// ---------------- K4: decode GEMM + running max (one WG per t) ---------------
__launch_bounds__(256)
__global__ void k_decode(const unsigned short* __restrict__ hd,
                         const unsigned short* __restrict__ dwb,
                         u32* __restrict__ key) {
    const int t    = blockIdx.x;
    const int tid  = threadIdx.x;
    const int lane = tid & 63;
    const int w    = tid >> 6;
    const int l15  = lane & 15;
    const int lk8  = (lane >> 4) * 8;
    const int brow = w * 16 + l15;

    const unsigned short* abase = hd + ((size_t)t * 64 + brow) * HIDN;
    f32x4 acc[7];
    #pragma unroll
    for (int nb = 0; nb < 7; ++nb) acc[nb] = (f32x4){0.f, 0.f, 0.f, 0.f};

    #pragma unroll
    for (int kk = 0; kk < 16; ++kk) {
        short8 a = *reinterpret_cast<const short8*>(abase + kk * 32 + lk8);
        #pragma unroll
        for (int nb = 0; nb < 7; ++nb) {
            short8 b = *reinterpret_cast<const short8*>(
                dwb + (size_t)(nb * 16 + l15) * HIDN + kk * 32 + lk8);
            acc[nb] = __builtin_amdgcn_mfma_f32_16x16x32_bf16(a, b, acc[nb], 0, 0, 0);
        }
    }
    #pragma unroll
    for (int nb = 0; nb < 7; ++nb) {
        int n = nb * 16 + l15;
        if (n < EMBD) {
            #pragma unroll
            for (int r = 0; r < 4; ++r) {
                int b = w * 16 + (lane >> 4) * 4 + r;
                u32 u  = __float_as_uint(acc[nb][r]);
                u32 kv = (u & 0x80000000u) ? ~u : (u | 0x80000000u);  // order-preserving
                atomicMax(&key[b * EMBD + n], kv);
            }
        }
    }
}

// ---------------- K5: inverse transform + decoder bias -----------------------
__global__ void k_final(const u32* __restrict__ key, const float* __restrict__ db,
                        float* __restrict__ out) {
    int i = blockIdx.x * 256 + threadIdx.x;
    if (i < BATCH * EMBD) {
        u32 k = key[i];
        u32 u = (k & 0x80000000u) ? (k & 0x7fffffffu) : ~k;
        out[i] = __uint_as_float(u) + db[i % EMBD];
    }
}

extern "C" void kernel_launch(void* const* d_in, const int* in_sizes, int n_in,
                              void* d_out, int out_size, void* d_ws, size_t ws_size,
                              hipStream_t stream) {
    const int*   x   = (const int*)d_in[0];
    const float* emb = (const float*)d_in[1];
    const float* wih = (const float*)d_in[2];
    const float* whh = (const float*)d_in[3];
    const float* bih = (const float*)d_in[4];
    const float* bhh = (const float*)d_in[5];
    const float* gam = (const float*)d_in[6];
    const float* bet = (const float*)d_in[7];
    const float* dw  = (const float*)d_in[8];
    const float* db  = (const float*)d_in[9];
    const float* msk = (const float*)d_in[10];

    char* ws = (char*)d_ws;
    unsigned short* A   = (unsigned short*)(ws + A_OFF);
    unsigned short* hd  = (unsigned short*)(ws + HD_OFF);
    u32*            hx  = (u32*)(ws + HB_OFF);
    u32*            flg = (u32*)(ws + FLG_OFF);
    u32*            key = (u32*)(ws + KEY_OFF);
    unsigned short* dwb = (unsigned short*)(ws + DW_OFF);

    hipMemsetAsync(ws + HB_OFF, 0, ZERO_SPAN, stream);      // granule tags + flags + keys
    k_dw    <<<224,  256, 0, stream>>>(dw, dwb);
    k_embed <<<8192, 256, 0, stream>>>(x, emb, A);
    k_lstm  <<<NWG,  512, 0, stream>>>(wih, whh, bih, bhh, gam, bet, msk, A, hx, hd, flg);
    k_decode<<<TSEQ, 256, 0, stream>>>(hd, dwb, key);
    k_final <<<25,   256, 0, stream>>>(key, db, (float*)d_out);
}